// Round 1
// baseline (689.518 us; speedup 1.0000x reference)
//
#include <hip/hip_runtime.h>

// Shapes: B=4, W=64, H=64, C=256, M=32, D=32. TEMPERATURE = 8.0.
// q: [B,W,H,M,D] f32; v: [B,W,H,C,M] f32; k: [B,W,H,D,1] f32
// out: [B,C,W,H] f32
//
// v4: split into two kernels through d_ws.
//  - attn_kernel: logits + softmax for all 16384 pixels -> ws[p][m] (2 MiB).
//    (phases A-C of the previous kernel, unchanged math/order)
//  - pv_kernel: out[c] = sum_m v[p,c,m]*attn[p,m] as a pure stream:
//    4096 blocks (16 px x 64-c slice), 6.4 KiB LDS, no interior barriers,
//    32 waves/CU. v loads 1 KiB/wave coalesced non-temporal; out written as
//    full 64 B lines non-temporal. Same 8-lane shuffle-tree reduction ->
//    bit-identical numerics to the passing v3 kernel.

#define TEMP_INV 0.125f
#define G 16        // pixels per block (64 B out line == 16 px)
#define CSPLIT 4    // c-range split for pv_kernel
#define CB (256 / CSPLIT)

typedef float f4 __attribute__((ext_vector_type(4)));

__global__ __launch_bounds__(256) void attn_kernel(
    const float* __restrict__ q,
    const float* __restrict__ k,
    float* __restrict__ attn_out)
{
    const int t  = threadIdx.x;
    const int p0 = blockIdx.x * G;

    __shared__ float s_k[G * 32];
    __shared__ float s_logit[G * 32];
    __shared__ float s_attn[G * 32];

    // k for all 16 pixels (128 float4, coalesced; reused -> normal load)
    if (t < 128) {
        f4 k4 = ((const f4*)k)[p0 * 8 + t];
        k4 *= TEMP_INV;
        ((f4*)s_k)[t] = k4;
    }
    __syncthreads();

    // logits: thread t = (m = t>>3, d-chunk j = t&7) per pixel
    const int j = t & 7;
    const int m = t >> 3;
    #pragma unroll 4
    for (int g = 0; g < G; ++g) {
        const f4 q4 = __builtin_nontemporal_load((const f4*)q + (p0 + g) * 256 + t);
        const float* kg = &s_k[g * 32 + j * 4];
        float partial = q4.x * kg[0] + q4.y * kg[1] + q4.z * kg[2] + q4.w * kg[3];
        partial += __shfl_down(partial, 4, 8);
        partial += __shfl_down(partial, 2, 8);
        partial += __shfl_down(partial, 1, 8);
        if (j == 0) s_logit[g * 32 + m] = partial;
    }
    __syncthreads();

    // softmax over the 32 slots per pixel; 8 pixels/pass x2
    {
        const int mm = t & 31;
        #pragma unroll
        for (int r = 0; r < 2; ++r) {
            const int g = (t >> 5) + r * 8;
            float l = s_logit[g * 32 + mm];
            float mx = l;
            #pragma unroll
            for (int off = 16; off; off >>= 1)
                mx = fmaxf(mx, __shfl_xor(mx, off, 32));
            float e = __expf(l - mx);
            float s = e;
            #pragma unroll
            for (int off = 16; off; off >>= 1)
                s += __shfl_xor(s, off, 32);
            s_attn[g * 32 + mm] = e / s;
        }
    }
    __syncthreads();

    // dump attn for these 16 pixels (2 KiB, coalesced, keep cacheable for pv)
    if (t < 128)
        ((f4*)attn_out)[p0 * 8 + t] = ((f4*)s_attn)[t];
}

__global__ __launch_bounds__(256) void pv_kernel(
    const float* __restrict__ v,
    const float* __restrict__ attn,
    float* __restrict__ out)
{
    const int t   = threadIdx.x;
    const int blk = blockIdx.x;
    const int p0  = (blk >> 2) * G;          // pixel group (16 px)
    const int c0  = (blk & 3) * CB;          // 64-c slice
    const int b   = p0 >> 12;
    const int wh0 = p0 & 4095;

    __shared__ float s_attn[G * 32];
    __shared__ float s_out[CB * 17];         // [c][g], pad 17 -> conflict-free

    // attn tile: 2 KiB, coalesced (just written by attn_kernel -> L2/L3 hit)
    if (t < 128)
        ((f4*)s_attn)[t] = ((const f4*)attn)[p0 * 8 + t];
    __syncthreads();

    // stream: per g, 64 c rows x 32 m = 8 KiB, 2 f4 loads/thread, coalesced
    const int j  = t & 7;      // m-chunk
    const int cr = t >> 3;     // 0..31 c row within half-slice
    #pragma unroll 4
    for (int g = 0; g < G; ++g) {
        const float* ag = &s_attn[g * 32 + j * 4];
        const float a0 = ag[0], a1 = ag[1], a2 = ag[2], a3 = ag[3];
        const f4* v4p = (const f4*)v + (size_t)(p0 + g) * 2048 + c0 * 8;
        f4 v40 = __builtin_nontemporal_load(v4p + t);
        f4 v41 = __builtin_nontemporal_load(v4p + t + 256);
        float acc0 = v40.x * a0 + v40.y * a1 + v40.z * a2 + v40.w * a3;
        float acc1 = v41.x * a0 + v41.y * a1 + v41.z * a2 + v41.w * a3;
        acc0 += __shfl_down(acc0, 4, 8);
        acc0 += __shfl_down(acc0, 2, 8);
        acc0 += __shfl_down(acc0, 1, 8);
        acc1 += __shfl_down(acc1, 4, 8);
        acc1 += __shfl_down(acc1, 2, 8);
        acc1 += __shfl_down(acc1, 1, 8);
        if (j == 0) {
            s_out[cr * 17 + g]        = acc0;
            s_out[(cr + 32) * 17 + g] = acc1;
        }
    }
    __syncthreads();

    // write out[b, c0..c0+63, wh0..wh0+15] — full 64 B lines, non-temporal
    {
        const int c  = t >> 2;   // 0..63 within slice
        const int gc = t & 3;    // float4 within the 16-px row
        const float* so = &s_out[c * 17 + gc * 4];
        f4 o4 = { so[0], so[1], so[2], so[3] };
        __builtin_nontemporal_store(
            o4, (f4*)out + (size_t)(b * 256 + c0 + c) * 1024 + (wh0 >> 2) + gc);
    }
}

extern "C" void kernel_launch(void* const* d_in, const int* in_sizes, int n_in,
                              void* d_out, int out_size, void* d_ws, size_t ws_size,
                              hipStream_t stream) {
    const float* q = (const float*)d_in[0];
    const float* v = (const float*)d_in[1];
    const float* k = (const float*)d_in[2];
    float* out = (float*)d_out;
    float* attn = (float*)d_ws;   // 16384 * 32 * 4 B = 2 MiB

    attn_kernel<<<16384 / G, 256, 0, stream>>>(q, k, attn);
    pv_kernel<<<(16384 / G) * CSPLIT, 256, 0, stream>>>(v, attn, out);
}